// Round 8
// baseline (220.532 us; speedup 1.0000x reference)
//
#include <hip/hip_runtime.h>

// ---------------------------------------------------------------------------
// GNN 2-layer via bf16 MFMA + CSR gather (no global atomics).
// Round 8 = Round-6 (best, 205.5us) + gather1/gemm2 half-overlap:
//   gemm2 row r needs only agg1[r] -> split at node Nh:
//   K5: gather1 [0,Nh)   K6: gather1 [Nh,N) || gemm2 [0,Nh)   K7: gemm2 [Nh,N)
// R7's build parallelization REVERTED (4x redundant histograms +10us).
// Launches:
//   K1: pack_w || binA        K2: binB
//   K3: binC || gemm1[0..gbA) K4: binD || gemm1[gbA..)
//   K5: gather1 first half
//   K6: gather1 second half || gemm2 first half
//   K7: gemm2 second half
//   K8: gather2 -> out[:, :128] fp32
// ws: m1bf | agg1bf | m2bf | W1p | W2p | mat | matc | bb | offs | tmp | bsrc
// ---------------------------------------------------------------------------

#define D 128
#define CBLK 256         // coarse-binning blocks (phases A and C)
#define DCAP 6144        // max edges per coarse bucket for LDS path

typedef __attribute__((ext_vector_type(8))) short short8;
typedef __attribute__((ext_vector_type(4))) float float4v;
typedef unsigned short ushort_t;
typedef unsigned int uint_t;

static __device__ __forceinline__ ushort_t f2bf(float f) {
    uint_t u = __builtin_bit_cast(uint_t, f);
    u += 0x7FFFu + ((u >> 16) & 1u);           // RNE
    return (ushort_t)(u >> 16);
}
static __device__ __forceinline__ float bfhi(uint_t u) {
    return __builtin_bit_cast(float, u & 0xFFFF0000u);
}
static __device__ __forceinline__ float bflo(uint_t u) {
    return __builtin_bit_cast(float, u << 16);
}

// ---------------- shared gemm1 body: 64-row tile, wave = 16 rows ------------
static __device__ __forceinline__ void gemm1_body(
    const float* __restrict__ X, const ushort_t* __restrict__ Wp,
    const float* __restrict__ bias, ushort_t* __restrict__ Ybf,
    int N, int gb)
{
    const int wave = threadIdx.x >> 6;
    const int lane = threadIdx.x & 63;
    const int quad = lane >> 4;
    const int l16  = lane & 15;
    const int r0   = gb * 64 + wave * 16;

    float4v acc[8];
    #pragma unroll
    for (int cg = 0; cg < 8; ++cg) {
        float bv = bias[cg * 16 + l16];
        float4v b4 = {bv, bv, bv, bv};
        acc[cg] = b4;
    }

    const short8* wp8 = (const short8*)Wp;

    #pragma unroll
    for (int kb = 0; kb < 4; ++kb) {
        const int k0 = kb * 32 + quad * 8;
        int row = r0 + l16;
        if (row >= N) row = N - 1;
        const float* p = &X[(size_t)row * D + k0];
        float4 x0 = *(const float4*)p;
        float4 x1 = *(const float4*)(p + 4);
        short8 a;
        a[0] = (short)f2bf(x0.x); a[1] = (short)f2bf(x0.y);
        a[2] = (short)f2bf(x0.z); a[3] = (short)f2bf(x0.w);
        a[4] = (short)f2bf(x1.x); a[5] = (short)f2bf(x1.y);
        a[6] = (short)f2bf(x1.z); a[7] = (short)f2bf(x1.w);
        #pragma unroll
        for (int cg = 0; cg < 8; ++cg) {
            short8 b = wp8[(kb * 8 + cg) * 64 + lane];
            acc[cg] = __builtin_amdgcn_mfma_f32_16x16x32_bf16(a, b, acc[cg], 0, 0, 0);
        }
    }

    const int rowb = r0 + quad * 4;
    #pragma unroll
    for (int cg = 0; cg < 8; ++cg) {
        int col = cg * 16 + l16;
        #pragma unroll
        for (int i = 0; i < 4; ++i) {
            int row = rowb + i;
            if (row < N) Ybf[(size_t)row * D + col] = f2bf(acc[cg][i]);
        }
    }
}

// ---------------- shared gemm2 body: 64-row tile ----------------------------
static __device__ __forceinline__ void gemm2_body(
    const ushort_t* __restrict__ A0, const ushort_t* __restrict__ A1,
    const ushort_t* __restrict__ Wp, const float* __restrict__ bias,
    float* __restrict__ Yf, ushort_t* __restrict__ Ybf, int N, int gb)
{
    const int wave = threadIdx.x >> 6;
    const int lane = threadIdx.x & 63;
    const int quad = lane >> 4;
    const int l16  = lane & 15;
    const int r0   = gb * 64 + wave * 16;

    float4v acc[8];
    #pragma unroll
    for (int cg = 0; cg < 8; ++cg) {
        float bv = bias[cg * 16 + l16];
        float4v b4 = {bv, bv, bv, bv};
        acc[cg] = b4;
    }

    const short8* wp8 = (const short8*)Wp;

    #pragma unroll
    for (int kb = 0; kb < 8; ++kb) {
        const ushort_t* __restrict__ A = (kb < 4) ? A0 : A1;
        const int k0 = (kb & 3) * 32 + quad * 8;
        int row = r0 + l16;
        if (row >= N) row = N - 1;
        short8 a = *(const short8*)&A[(size_t)row * D + k0];
        #pragma unroll
        for (int cg = 0; cg < 8; ++cg) {
            short8 b = wp8[(kb * 8 + cg) * 64 + lane];
            acc[cg] = __builtin_amdgcn_mfma_f32_16x16x32_bf16(a, b, acc[cg], 0, 0, 0);
        }
    }

    const int rowb = r0 + quad * 4;
    #pragma unroll
    for (int cg = 0; cg < 8; ++cg) {
        int col = cg * 16 + l16;
        #pragma unroll
        for (int i = 0; i < 4; ++i) {
            int row = rowb + i;
            if (row < N) {
                float v = acc[cg][i];
                Yf[(size_t)row * 256 + col] = v;
                Ybf[(size_t)row * D + col] = f2bf(v);
            }
        }
    }
}

// ---------------- shared gather body (one node per wave) --------------------
static __device__ __forceinline__ void gather_body(
    const ushort_t* __restrict__ msg,
    const int* __restrict__ offs, const int* __restrict__ bsrc,
    ushort_t* __restrict__ aggB, float* __restrict__ aggF, int node)
{
    const int lane = threadIdx.x & 63;
    const int quad = lane >> 4;
    const int c16  = lane & 15;
    int beg = offs[node], end = offs[node + 1];

    float ax[4] = {0.f, 0.f, 0.f, 0.f};
    float ay[4] = {0.f, 0.f, 0.f, 0.f};
    const uint4* mp = (const uint4*)msg;         // 16 uint4 per row

    for (int base = beg; base < end; base += 64) {
        int cnt = end - base; if (cnt > 64) cnt = 64;
        int sidx = bsrc[base + (lane < cnt ? lane : cnt - 1)];
        for (int j0 = 0; j0 < cnt; j0 += 16) {
            #pragma unroll
            for (int t = 0; t < 4; ++t) {
                int e  = j0 + t * 4 + quad;
                int ec = (e < cnt) ? e : cnt - 1;
                int s  = __shfl(sidx, ec, 64);
                uint4 u = mp[(size_t)s * 16 + c16];
                if (e < cnt) {
                    ax[0] += bflo(u.x); ay[0] += bfhi(u.x);
                    ax[1] += bflo(u.y); ay[1] += bfhi(u.y);
                    ax[2] += bflo(u.z); ay[2] += bfhi(u.z);
                    ax[3] += bflo(u.w); ay[3] += bfhi(u.w);
                }
            }
        }
    }

    #pragma unroll
    for (int k = 0; k < 4; ++k) {
        ax[k] += __shfl_xor(ax[k], 16, 64);
        ax[k] += __shfl_xor(ax[k], 32, 64);
        ay[k] += __shfl_xor(ay[k], 16, 64);
        ay[k] += __shfl_xor(ay[k], 32, 64);
    }

    if (quad == 0) {
        if (aggB) {
            uint4 o;
            o.x = (uint_t)f2bf(ax[0]) | ((uint_t)f2bf(ay[0]) << 16);
            o.y = (uint_t)f2bf(ax[1]) | ((uint_t)f2bf(ay[1]) << 16);
            o.z = (uint_t)f2bf(ax[2]) | ((uint_t)f2bf(ay[2]) << 16);
            o.w = (uint_t)f2bf(ax[3]) | ((uint_t)f2bf(ay[3]) << 16);
            ((uint4*)aggB)[(size_t)node * 16 + c16] = o;
        } else {
            float4 w0 = {ax[0], ay[0], ax[1], ay[1]};
            float4 w1 = {ax[2], ay[2], ax[3], ay[3]};
            float* p = &aggF[(size_t)node * 256 + c16 * 8];
            *(float4*)p = w0;
            *(float4*)(p + 4) = w1;
        }
    }
}

// ---------------- K1: pack both W (B-frag layout)  ||  binA -----------------
__global__ __launch_bounds__(256) void packw_binA(
    const float* __restrict__ W1, const float* __restrict__ W2,
    ushort_t* __restrict__ W1p, ushort_t* __restrict__ W2p,
    const int* __restrict__ dst, int* __restrict__ mat, int E, int NB)
{
    __shared__ int h[256];
    if (blockIdx.x < CBLK) {
        const int c = blockIdx.x;
        for (int i = threadIdx.x; i < NB; i += 256) h[i] = 0;
        __syncthreads();
        const int chunk = (E + CBLK - 1) / CBLK;
        int e0 = c * chunk, e1 = e0 + chunk; if (e1 > E) e1 = E;
        for (int e = e0 + threadIdx.x; e < e1; e += 256)
            atomicAdd(&h[dst[e] >> 8], 1);
        __syncthreads();
        for (int i = threadIdx.x; i < NB; i += 256)
            mat[i * CBLK + c] = h[i];
        return;
    }
    const int n1 = 4 * 8 * 64;
    const int n2 = 8 * 8 * 64;
    int t = (blockIdx.x - CBLK) * 256 + threadIdx.x;
    if (t >= n1 + n2) return;
    const float* W; ushort_t* Wp; int tt;
    if (t < n1) { W = W1; Wp = W1p; tt = t; }
    else        { W = W2; Wp = W2p; tt = t - n1; }
    int lane = tt & 63, cg = (tt >> 6) & 7, kb = tt >> 9;
    int krow = kb * 32 + (lane >> 4) * 8;
    int col  = cg * 16 + (lane & 15);
    #pragma unroll
    for (int j = 0; j < 8; ++j)
        Wp[(size_t)tt * 8 + j] = f2bf(W[(size_t)(krow + j) * D + col]);
}

// ---------------- K2: binB (merged B1+B2) -----------------------------------
__global__ __launch_bounds__(256) void binB(
    const int* __restrict__ mat, int* __restrict__ matc,
    int* __restrict__ bb, int* __restrict__ offs, int E, int N, int NB)
{
    __shared__ int s[256];
    __shared__ int ex[256];
    const int b = blockIdx.x;
    const int tid = threadIdx.x;

    int v = 0;
    if (tid < NB) {
        const int* row = &mat[tid * CBLK];
        for (int c = 0; c < CBLK; ++c) v += row[c];
    }
    s[tid] = v; __syncthreads();
    for (int o = 1; o < 256; o <<= 1) {
        int t = (tid >= o) ? s[tid - o] : 0;
        __syncthreads();
        s[tid] += t;
        __syncthreads();
    }
    ex[tid] = s[tid] - v;
    __syncthreads();
    if (b == 0) {
        if (tid < NB) bb[tid] = ex[tid];
        if (tid == 0) { bb[NB] = E; offs[N] = E; }
    }
    const int bbb = ex[b];

    int v2 = mat[b * CBLK + tid];
    __syncthreads();
    s[tid] = v2; __syncthreads();
    for (int o = 1; o < 256; o <<= 1) {
        int t = (tid >= o) ? s[tid - o] : 0;
        __syncthreads();
        s[tid] += t;
        __syncthreads();
    }
    matc[b * CBLK + tid] = bbb + s[tid] - v2;
}

// ---------------- K3: binC  ||  gemm1 part A --------------------------------
__global__ __launch_bounds__(256) void binC_gemm1(
    const int* __restrict__ src, const int* __restrict__ dst,
    const int* __restrict__ matc, int2* __restrict__ tmp, int E, int NB,
    const float* __restrict__ X, const ushort_t* __restrict__ Wp,
    const float* __restrict__ bias, ushort_t* __restrict__ Ybf, int N)
{
    __shared__ int base[256];
    __shared__ int lcnt[256];
    if (blockIdx.x < CBLK) {
        const int c = blockIdx.x;
        for (int i = threadIdx.x; i < NB; i += 256) {
            base[i] = matc[i * CBLK + c];
            lcnt[i] = 0;
        }
        __syncthreads();
        const int chunk = (E + CBLK - 1) / CBLK;
        int e0 = c * chunk, e1 = e0 + chunk; if (e1 > E) e1 = E;
        for (int e = e0 + threadIdx.x; e < e1; e += 256) {
            int d = dst[e];
            int b = d >> 8;
            int p = base[b] + atomicAdd(&lcnt[b], 1);
            int2 pr; pr.x = d; pr.y = src[e];
            tmp[p] = pr;
        }
        return;
    }
    gemm1_body(X, Wp, bias, Ybf, N, blockIdx.x - CBLK);
}

// ---------------- K4: binD (fine sort) || gemm1 part B ----------------------
__global__ __launch_bounds__(256) void binD_gemm1(
    const int2* __restrict__ tmp, const int* __restrict__ bb,
    int* __restrict__ offs, int* __restrict__ bsrc, int N, int NB,
    const float* __restrict__ X, const ushort_t* __restrict__ Wp,
    const float* __restrict__ bias, ushort_t* __restrict__ Ybf, int gb0)
{
    __shared__ int hist[256];
    __shared__ int foff[256];
    __shared__ int cntf[256];
    __shared__ int outS[DCAP];
    if (blockIdx.x >= (uint_t)NB) {
        gemm1_body(X, Wp, bias, Ybf, N, blockIdx.x - NB + gb0);
        return;
    }
    const int b = blockIdx.x;
    const int tid = threadIdx.x;
    const int beg = bb[b], end = bb[b + 1];
    const int cnt = end - beg;
    const int n0 = b << 8;

    hist[tid] = 0;
    __syncthreads();
    for (int i = tid; i < cnt; i += 256)
        atomicAdd(&hist[tmp[beg + i].x & 255], 1);
    __syncthreads();
    int v = hist[tid];
    __syncthreads();
    hist[tid] = v; __syncthreads();
    for (int o = 1; o < 256; o <<= 1) {
        int t = (tid >= o) ? hist[tid - o] : 0;
        __syncthreads();
        hist[tid] += t;
        __syncthreads();
    }
    foff[tid] = hist[tid] - v;
    cntf[tid] = 0;
    __syncthreads();

    int node = n0 + tid;
    if (node < N) offs[node] = beg + foff[tid];

    if (cnt <= DCAP) {
        for (int i = tid; i < cnt; i += 256) {
            int2 p = tmp[beg + i];
            int f = p.x & 255;
            int pos = foff[f] + atomicAdd(&cntf[f], 1);
            outS[pos] = p.y;
        }
        __syncthreads();
        for (int i = tid; i < cnt; i += 256)
            bsrc[beg + i] = outS[i];
    } else {
        for (int i = tid; i < cnt; i += 256) {
            int2 p = tmp[beg + i];
            int f = p.x & 255;
            int pos = foff[f] + atomicAdd(&cntf[f], 1);
            bsrc[beg + pos] = p.y;
        }
    }
}

// ---------------- K5: gather1 nodes [0, Nh) ---------------------------------
__global__ __launch_bounds__(256) void gather1_a(
    const ushort_t* __restrict__ msg,
    const int* __restrict__ offs, const int* __restrict__ bsrc,
    ushort_t* __restrict__ aggB, int Nh)
{
    int node = (blockIdx.x * 256 + threadIdx.x) >> 6;
    if (node >= Nh) return;
    gather_body(msg, offs, bsrc, aggB, nullptr, node);
}

// ---------------- K6: gather1 nodes [Nh, N)  ||  gemm2 tiles [0, gH) --------
__global__ __launch_bounds__(256) void gather1b_gemm2a(
    const ushort_t* __restrict__ msg,
    const int* __restrict__ offs, const int* __restrict__ bsrc,
    ushort_t* __restrict__ aggB, int Nh, int N, int GB,
    const ushort_t* __restrict__ A0, const ushort_t* __restrict__ Wp,
    const float* __restrict__ bias, float* __restrict__ Yf,
    ushort_t* __restrict__ Ybf)
{
    if ((int)blockIdx.x < GB) {
        int node = Nh + (int)((blockIdx.x * 256 + threadIdx.x) >> 6);
        if (node >= N) return;
        gather_body(msg, offs, bsrc, aggB, nullptr, node);
        return;
    }
    gemm2_body(A0, msg, Wp, bias, Yf, Ybf, N, blockIdx.x - GB);
}

// ---------------- K7: gemm2 tiles [gH, gemmBlocks) --------------------------
__global__ __launch_bounds__(256) void gemm2_b(
    const ushort_t* __restrict__ A0, const ushort_t* __restrict__ A1,
    const ushort_t* __restrict__ Wp, const float* __restrict__ bias,
    float* __restrict__ Yf, ushort_t* __restrict__ Ybf, int N, int gb0)
{
    gemm2_body(A0, A1, Wp, bias, Yf, Ybf, N, blockIdx.x + gb0);
}

// ---------------- K8: gather2 all nodes -> fp32 out[:, :128] ----------------
__global__ __launch_bounds__(256) void gather2(
    const ushort_t* __restrict__ msg,
    const int* __restrict__ offs, const int* __restrict__ bsrc,
    float* __restrict__ aggF, int N)
{
    int node = (blockIdx.x * 256 + threadIdx.x) >> 6;
    if (node >= N) return;
    gather_body(msg, offs, bsrc, nullptr, aggF, node);
}

// ---------------------------------------------------------------------------
extern "C" void kernel_launch(void* const* d_in, const int* in_sizes, int n_in,
                              void* d_out, int out_size, void* d_ws, size_t ws_size,
                              hipStream_t stream) {
    const float* features = (const float*)d_in[0];
    const int*   src      = (const int*)d_in[1];
    const int*   dst      = (const int*)d_in[2];
    const float* W1       = (const float*)d_in[3];
    const float* b1       = (const float*)d_in[4];
    const float* W2       = (const float*)d_in[5];
    const float* b2       = (const float*)d_in[6];
    float* out = (float*)d_out;

    const int N = in_sizes[0] / D;   // 50000
    const int E = in_sizes[1];       // 800000
    const int NB = (N + 255) >> 8;   // 196 coarse buckets (<=256 required)

    // ws carve-up
    ushort_t* m1bf   = (ushort_t*)d_ws;                 // N*D
    ushort_t* agg1bf = m1bf + (size_t)N * D;            // N*D
    ushort_t* m2bf   = agg1bf + (size_t)N * D;          // N*D
    ushort_t* W1p    = m2bf + (size_t)N * D;            // 16384
    ushort_t* W2p    = W1p + 16384;                     // 32768
    int*  mat  = (int*)(W2p + 32768);                   // NB*CBLK (histograms)
    int*  matc = mat + (size_t)NB * CBLK;               // NB*CBLK (cursors)
    int*  bb   = matc + (size_t)NB * CBLK;              // NB+1
    int*  offs = bb + NB + 1;                           // N+1
    int2* tmp  = (int2*)(offs + N + 1);                 // E pairs
    int*  bsrc = (int*)(tmp + (size_t)E);               // E

    const int gemmBlocks = (N + 63) / 64;               // 782 (64-row tiles)
    const int gbA = (gemmBlocks * 3) / 5;               // gemm1 share in K3

    const int Nh = ((N / 2) + 63) & ~63;                // 25024, tile-aligned
    const int gH = Nh / 64;                             // gemm2 tiles in K6
    const int g1aBlocks = (Nh * 64 + 255) / 256;        // 6256
    const int g1bBlocks = ((N - Nh) * 64 + 255) / 256;  // 6244

    // K1: weight pack || coarse histogram
    packw_binA<<<CBLK + 24, 256, 0, stream>>>(W1, W2, W1p, W2p, dst, mat, E, NB);
    // K2: merged scans -> bucket bases (bb) + per-block cursors (matc)
    binB<<<NB, 256, 0, stream>>>(mat, matc, bb, offs, E, N, NB);
    // K3: coarse binning || gemm1 tiles [0, gbA)
    binC_gemm1<<<CBLK + gbA, 256, 0, stream>>>(src, dst, matc, tmp, E, NB,
                                               features, W1p, b1, m1bf, N);
    // K4: fine sort || gemm1 tiles [gbA, gemmBlocks)
    binD_gemm1<<<NB + (gemmBlocks - gbA), 256, 0, stream>>>(
        tmp, bb, offs, bsrc, N, NB, features, W1p, b1, m1bf, gbA);
    // K5: layer-1 gather, nodes [0, Nh)
    gather1_a<<<g1aBlocks, 256, 0, stream>>>(m1bf, offs, bsrc, agg1bf, Nh);
    // K6: layer-1 gather [Nh, N) || gemm2 rows [0, Nh)
    gather1b_gemm2a<<<g1bBlocks + gH, 256, 0, stream>>>(
        m1bf, offs, bsrc, agg1bf, Nh, N, g1bBlocks,
        agg1bf, W2p, b2, out + D, m2bf);
    // K7: gemm2 rows [Nh, N)
    gemm2_b<<<gemmBlocks - gH, 256, 0, stream>>>(agg1bf, m1bf, W2p, b2,
                                                 out + D, m2bf, N, gH);
    // K8: layer-2 gather -> out[:, :128]
    gather2<<<(N * 64 + 255) / 256, 256, 0, stream>>>(m2bf, offs, bsrc, out, N);
}

// Round 9
// 211.492 us; speedup vs baseline: 1.0427x; 1.0427x over previous
//
#include <hip/hip_runtime.h>

// ---------------------------------------------------------------------------
// GNN 2-layer via bf16 MFMA + CSR gather (no global atomics).
// Round 9 = Round-6 base (best, 205.5us) + two local fixes:
//  - gathers: TWO nodes per wave, interleaved loads (8 row-loads in flight
//    vs 4; half the wave churn; quad0/quad1 write nodes A/B in parallel).
//    Gathers are latency-bound (deg~16 -> only 4 loads/wave in flight).
//  - binD: outS LDS staging dropped (direct 4B scatter within 16KB bucket
//    window stays L2-merged). K4 static LDS 27KB -> 3KB so co-resident
//    gemm1 tail blocks are no longer LDS-capped.
// Launches:
//   K1: pack_w || binA        K2: binB
//   K3: binC || gemm1[0..gbA) K4: binD || gemm1[gbA..)
//   K5: gather1 -> agg1bf     K6: gemm2 -> out[:,128:] + m2bf
//   K7: gather2 -> out[:, :128]
// ws: m1bf | agg1bf | m2bf | W1p | W2p | mat | matc | bb | offs | tmp | bsrc
// ---------------------------------------------------------------------------

#define D 128
#define CBLK 256         // coarse-binning blocks (phases A and C)

typedef __attribute__((ext_vector_type(8))) short short8;
typedef __attribute__((ext_vector_type(4))) float float4v;
typedef unsigned short ushort_t;
typedef unsigned int uint_t;

static __device__ __forceinline__ ushort_t f2bf(float f) {
    uint_t u = __builtin_bit_cast(uint_t, f);
    u += 0x7FFFu + ((u >> 16) & 1u);           // RNE
    return (ushort_t)(u >> 16);
}
static __device__ __forceinline__ float bfhi(uint_t u) {
    return __builtin_bit_cast(float, u & 0xFFFF0000u);
}
static __device__ __forceinline__ float bflo(uint_t u) {
    return __builtin_bit_cast(float, u << 16);
}

// ---------------- shared gemm1 body: 64-row tile, wave = 16 rows ------------
static __device__ __forceinline__ void gemm1_body(
    const float* __restrict__ X, const ushort_t* __restrict__ Wp,
    const float* __restrict__ bias, ushort_t* __restrict__ Ybf,
    int N, int gb)
{
    const int wave = threadIdx.x >> 6;
    const int lane = threadIdx.x & 63;
    const int quad = lane >> 4;
    const int l16  = lane & 15;
    const int r0   = gb * 64 + wave * 16;

    float4v acc[8];
    #pragma unroll
    for (int cg = 0; cg < 8; ++cg) {
        float bv = bias[cg * 16 + l16];
        float4v b4 = {bv, bv, bv, bv};
        acc[cg] = b4;
    }

    const short8* wp8 = (const short8*)Wp;

    #pragma unroll
    for (int kb = 0; kb < 4; ++kb) {
        const int k0 = kb * 32 + quad * 8;
        int row = r0 + l16;
        if (row >= N) row = N - 1;
        const float* p = &X[(size_t)row * D + k0];
        float4 x0 = *(const float4*)p;
        float4 x1 = *(const float4*)(p + 4);
        short8 a;
        a[0] = (short)f2bf(x0.x); a[1] = (short)f2bf(x0.y);
        a[2] = (short)f2bf(x0.z); a[3] = (short)f2bf(x0.w);
        a[4] = (short)f2bf(x1.x); a[5] = (short)f2bf(x1.y);
        a[6] = (short)f2bf(x1.z); a[7] = (short)f2bf(x1.w);
        #pragma unroll
        for (int cg = 0; cg < 8; ++cg) {
            short8 b = wp8[(kb * 8 + cg) * 64 + lane];
            acc[cg] = __builtin_amdgcn_mfma_f32_16x16x32_bf16(a, b, acc[cg], 0, 0, 0);
        }
    }

    const int rowb = r0 + quad * 4;
    #pragma unroll
    for (int cg = 0; cg < 8; ++cg) {
        int col = cg * 16 + l16;
        #pragma unroll
        for (int i = 0; i < 4; ++i) {
            int row = rowb + i;
            if (row < N) Ybf[(size_t)row * D + col] = f2bf(acc[cg][i]);
        }
    }
}

// ---------------- K1: pack both W (B-frag layout)  ||  binA -----------------
__global__ __launch_bounds__(256) void packw_binA(
    const float* __restrict__ W1, const float* __restrict__ W2,
    ushort_t* __restrict__ W1p, ushort_t* __restrict__ W2p,
    const int* __restrict__ dst, int* __restrict__ mat, int E, int NB)
{
    __shared__ int h[256];
    if (blockIdx.x < CBLK) {
        const int c = blockIdx.x;
        for (int i = threadIdx.x; i < NB; i += 256) h[i] = 0;
        __syncthreads();
        const int chunk = (E + CBLK - 1) / CBLK;
        int e0 = c * chunk, e1 = e0 + chunk; if (e1 > E) e1 = E;
        for (int e = e0 + threadIdx.x; e < e1; e += 256)
            atomicAdd(&h[dst[e] >> 8], 1);
        __syncthreads();
        for (int i = threadIdx.x; i < NB; i += 256)
            mat[i * CBLK + c] = h[i];
        return;
    }
    const int n1 = 4 * 8 * 64;
    const int n2 = 8 * 8 * 64;
    int t = (blockIdx.x - CBLK) * 256 + threadIdx.x;
    if (t >= n1 + n2) return;
    const float* W; ushort_t* Wp; int tt;
    if (t < n1) { W = W1; Wp = W1p; tt = t; }
    else        { W = W2; Wp = W2p; tt = t - n1; }
    int lane = tt & 63, cg = (tt >> 6) & 7, kb = tt >> 9;
    int krow = kb * 32 + (lane >> 4) * 8;
    int col  = cg * 16 + (lane & 15);
    #pragma unroll
    for (int j = 0; j < 8; ++j)
        Wp[(size_t)tt * 8 + j] = f2bf(W[(size_t)(krow + j) * D + col]);
}

// ---------------- K2: binB (merged B1+B2) -----------------------------------
__global__ __launch_bounds__(256) void binB(
    const int* __restrict__ mat, int* __restrict__ matc,
    int* __restrict__ bb, int* __restrict__ offs, int E, int N, int NB)
{
    __shared__ int s[256];
    __shared__ int ex[256];
    const int b = blockIdx.x;
    const int tid = threadIdx.x;

    int v = 0;
    if (tid < NB) {
        const int* row = &mat[tid * CBLK];
        for (int c = 0; c < CBLK; ++c) v += row[c];
    }
    s[tid] = v; __syncthreads();
    for (int o = 1; o < 256; o <<= 1) {
        int t = (tid >= o) ? s[tid - o] : 0;
        __syncthreads();
        s[tid] += t;
        __syncthreads();
    }
    ex[tid] = s[tid] - v;
    __syncthreads();
    if (b == 0) {
        if (tid < NB) bb[tid] = ex[tid];
        if (tid == 0) { bb[NB] = E; offs[N] = E; }
    }
    const int bbb = ex[b];

    int v2 = mat[b * CBLK + tid];
    __syncthreads();
    s[tid] = v2; __syncthreads();
    for (int o = 1; o < 256; o <<= 1) {
        int t = (tid >= o) ? s[tid - o] : 0;
        __syncthreads();
        s[tid] += t;
        __syncthreads();
    }
    matc[b * CBLK + tid] = bbb + s[tid] - v2;
}

// ---------------- K3: binC  ||  gemm1 part A --------------------------------
__global__ __launch_bounds__(256) void binC_gemm1(
    const int* __restrict__ src, const int* __restrict__ dst,
    const int* __restrict__ matc, int2* __restrict__ tmp, int E, int NB,
    const float* __restrict__ X, const ushort_t* __restrict__ Wp,
    const float* __restrict__ bias, ushort_t* __restrict__ Ybf, int N)
{
    __shared__ int base[256];
    __shared__ int lcnt[256];
    if (blockIdx.x < CBLK) {
        const int c = blockIdx.x;
        for (int i = threadIdx.x; i < NB; i += 256) {
            base[i] = matc[i * CBLK + c];
            lcnt[i] = 0;
        }
        __syncthreads();
        const int chunk = (E + CBLK - 1) / CBLK;
        int e0 = c * chunk, e1 = e0 + chunk; if (e1 > E) e1 = E;
        for (int e = e0 + threadIdx.x; e < e1; e += 256) {
            int d = dst[e];
            int b = d >> 8;
            int p = base[b] + atomicAdd(&lcnt[b], 1);
            int2 pr; pr.x = d; pr.y = src[e];
            tmp[p] = pr;
        }
        return;
    }
    gemm1_body(X, Wp, bias, Ybf, N, blockIdx.x - CBLK);
}

// ---------------- K4: binD (fine sort, direct scatter) || gemm1 part B ------
__global__ __launch_bounds__(256) void binD_gemm1(
    const int2* __restrict__ tmp, const int* __restrict__ bb,
    int* __restrict__ offs, int* __restrict__ bsrc, int N, int NB,
    const float* __restrict__ X, const ushort_t* __restrict__ Wp,
    const float* __restrict__ bias, ushort_t* __restrict__ Ybf, int gb0)
{
    __shared__ int hist[256];
    __shared__ int foff[256];
    __shared__ int cntf[256];
    if (blockIdx.x >= (uint_t)NB) {
        gemm1_body(X, Wp, bias, Ybf, N, blockIdx.x - NB + gb0);
        return;
    }
    const int b = blockIdx.x;
    const int tid = threadIdx.x;
    const int beg = bb[b], end = bb[b + 1];
    const int cnt = end - beg;
    const int n0 = b << 8;

    hist[tid] = 0;
    __syncthreads();
    for (int i = tid; i < cnt; i += 256)
        atomicAdd(&hist[tmp[beg + i].x & 255], 1);
    __syncthreads();
    int v = hist[tid];
    __syncthreads();
    hist[tid] = v; __syncthreads();
    for (int o = 1; o < 256; o <<= 1) {
        int t = (tid >= o) ? hist[tid - o] : 0;
        __syncthreads();
        hist[tid] += t;
        __syncthreads();
    }
    foff[tid] = hist[tid] - v;
    cntf[tid] = 0;
    __syncthreads();

    int node = n0 + tid;
    if (node < N) offs[node] = beg + foff[tid];

    // direct scatter: 4B writes within the 16KB bucket window merge in L2
    for (int i = tid; i < cnt; i += 256) {
        int2 p = tmp[beg + i];
        int f = p.x & 255;
        int pos = foff[f] + atomicAdd(&cntf[f], 1);
        bsrc[beg + pos] = p.y;
    }
}

// ---------------- K6: MFMA GEMM 2 (64-row tile): bf16 A0/A1 -> fp32 + bf16 --
__global__ __launch_bounds__(256) void gemm2_mfma(
    const ushort_t* __restrict__ A0, const ushort_t* __restrict__ A1,
    const ushort_t* __restrict__ Wp, const float* __restrict__ bias,
    float* __restrict__ Yf, ushort_t* __restrict__ Ybf, int N)
{
    const int wave = threadIdx.x >> 6;
    const int lane = threadIdx.x & 63;
    const int quad = lane >> 4;
    const int l16  = lane & 15;
    const int r0   = blockIdx.x * 64 + wave * 16;

    float4v acc[8];
    #pragma unroll
    for (int cg = 0; cg < 8; ++cg) {
        float bv = bias[cg * 16 + l16];
        float4v b4 = {bv, bv, bv, bv};
        acc[cg] = b4;
    }

    const short8* wp8 = (const short8*)Wp;

    #pragma unroll
    for (int kb = 0; kb < 8; ++kb) {
        const ushort_t* __restrict__ A = (kb < 4) ? A0 : A1;
        const int k0 = (kb & 3) * 32 + quad * 8;
        int row = r0 + l16;
        if (row >= N) row = N - 1;
        short8 a = *(const short8*)&A[(size_t)row * D + k0];
        #pragma unroll
        for (int cg = 0; cg < 8; ++cg) {
            short8 b = wp8[(kb * 8 + cg) * 64 + lane];
            acc[cg] = __builtin_amdgcn_mfma_f32_16x16x32_bf16(a, b, acc[cg], 0, 0, 0);
        }
    }

    const int rowb = r0 + quad * 4;
    #pragma unroll
    for (int cg = 0; cg < 8; ++cg) {
        int col = cg * 16 + l16;
        #pragma unroll
        for (int i = 0; i < 4; ++i) {
            int row = rowb + i;
            if (row < N) {
                float v = acc[cg][i];
                Yf[(size_t)row * 256 + col] = v;
                Ybf[(size_t)row * D + col] = f2bf(v);
            }
        }
    }
}

// ---------------- K5/K7: gather-sum, TWO nodes per wave ---------------------
// Wave w handles nodes 2w, 2w+1 with interleaved loads (8 row-loads in
// flight). After the cross-quad reduce every lane holds both totals;
// quad0 writes node A, quad1 writes node B (parallel write-out).
__global__ __launch_bounds__(256) void gather_bf(
    const ushort_t* __restrict__ msg,            // [N][128] bf16
    const int* __restrict__ offs, const int* __restrict__ bsrc,
    ushort_t* __restrict__ aggB,                 // bf16 out [N][128], or null
    float* __restrict__ aggF,                    // fp32 out (stride 256), or null
    int N)
{
    int w = (blockIdx.x * 256 + threadIdx.x) >> 6;
    int nA = w * 2;
    if (nA >= N) return;
    const int lane = threadIdx.x & 63;
    const int quad = lane >> 4;
    const int c16  = lane & 15;
    const bool hasB = (nA + 1) < N;

    const int begA = offs[nA],     endA = offs[nA + 1];
    const int begB = hasB ? offs[nA + 1] : 0;
    const int endB = hasB ? offs[nA + 2] : 0;

    float axA[4] = {0.f,0.f,0.f,0.f}, ayA[4] = {0.f,0.f,0.f,0.f};
    float axB[4] = {0.f,0.f,0.f,0.f}, ayB[4] = {0.f,0.f,0.f,0.f};
    const uint4* mp = (const uint4*)msg;         // 16 uint4 per row

    int baseA = begA, baseB = begB;
    while (baseA < endA || baseB < endB) {
        int cntA = endA - baseA; cntA = cntA > 64 ? 64 : cntA;
        int cntB = endB - baseB; cntB = cntB > 64 ? 64 : cntB;
        int sidxA = (cntA > 0) ? bsrc[baseA + (lane < cntA ? lane : cntA - 1)] : 0;
        int sidxB = (cntB > 0) ? bsrc[baseB + (lane < cntB ? lane : cntB - 1)] : 0;
        int mx = cntA > cntB ? cntA : cntB;
        for (int j0 = 0; j0 < mx; j0 += 16) {
            #pragma unroll
            for (int t = 0; t < 4; ++t) {
                int e = j0 + t * 4 + quad;
                int ecA = (e < cntA) ? e : (cntA > 0 ? cntA - 1 : 0);
                int ecB = (e < cntB) ? e : (cntB > 0 ? cntB - 1 : 0);
                int sA = __shfl(sidxA, ecA, 64);
                int sB = __shfl(sidxB, ecB, 64);
                uint4 uA = mp[(size_t)sA * 16 + c16];
                uint4 uB = mp[(size_t)sB * 16 + c16];
                if (e < cntA) {
                    axA[0] += bflo(uA.x); ayA[0] += bfhi(uA.x);
                    axA[1] += bflo(uA.y); ayA[1] += bfhi(uA.y);
                    axA[2] += bflo(uA.z); ayA[2] += bfhi(uA.z);
                    axA[3] += bflo(uA.w); ayA[3] += bfhi(uA.w);
                }
                if (e < cntB) {
                    axB[0] += bflo(uB.x); ayB[0] += bfhi(uB.x);
                    axB[1] += bflo(uB.y); ayB[1] += bfhi(uB.y);
                    axB[2] += bflo(uB.z); ayB[2] += bfhi(uB.z);
                    axB[3] += bflo(uB.w); ayB[3] += bfhi(uB.w);
                }
            }
        }
        baseA += cntA; baseB += cntB;
    }

    #pragma unroll
    for (int k = 0; k < 4; ++k) {
        axA[k] += __shfl_xor(axA[k], 16, 64);
        axA[k] += __shfl_xor(axA[k], 32, 64);
        ayA[k] += __shfl_xor(ayA[k], 16, 64);
        ayA[k] += __shfl_xor(ayA[k], 32, 64);
        axB[k] += __shfl_xor(axB[k], 16, 64);
        axB[k] += __shfl_xor(axB[k], 32, 64);
        ayB[k] += __shfl_xor(ayB[k], 16, 64);
        ayB[k] += __shfl_xor(ayB[k], 32, 64);
    }

    if (quad == 0) {
        if (aggB) {
            uint4 o;
            o.x = (uint_t)f2bf(axA[0]) | ((uint_t)f2bf(ayA[0]) << 16);
            o.y = (uint_t)f2bf(axA[1]) | ((uint_t)f2bf(ayA[1]) << 16);
            o.z = (uint_t)f2bf(axA[2]) | ((uint_t)f2bf(ayA[2]) << 16);
            o.w = (uint_t)f2bf(axA[3]) | ((uint_t)f2bf(ayA[3]) << 16);
            ((uint4*)aggB)[(size_t)nA * 16 + c16] = o;
        } else {
            float4 w0 = {axA[0], ayA[0], axA[1], ayA[1]};
            float4 w1 = {axA[2], ayA[2], axA[3], ayA[3]};
            float* p = &aggF[(size_t)nA * 256 + c16 * 8];
            *(float4*)p = w0;
            *(float4*)(p + 4) = w1;
        }
    } else if (quad == 1 && hasB) {
        if (aggB) {
            uint4 o;
            o.x = (uint_t)f2bf(axB[0]) | ((uint_t)f2bf(ayB[0]) << 16);
            o.y = (uint_t)f2bf(axB[1]) | ((uint_t)f2bf(ayB[1]) << 16);
            o.z = (uint_t)f2bf(axB[2]) | ((uint_t)f2bf(ayB[2]) << 16);
            o.w = (uint_t)f2bf(axB[3]) | ((uint_t)f2bf(ayB[3]) << 16);
            ((uint4*)aggB)[(size_t)(nA + 1) * 16 + c16] = o;
        } else {
            float4 w0 = {axB[0], ayB[0], axB[1], ayB[1]};
            float4 w1 = {axB[2], ayB[2], axB[3], ayB[3]};
            float* p = &aggF[(size_t)(nA + 1) * 256 + c16 * 8];
            *(float4*)p = w0;
            *(float4*)(p + 4) = w1;
        }
    }
}

// ---------------------------------------------------------------------------
extern "C" void kernel_launch(void* const* d_in, const int* in_sizes, int n_in,
                              void* d_out, int out_size, void* d_ws, size_t ws_size,
                              hipStream_t stream) {
    const float* features = (const float*)d_in[0];
    const int*   src      = (const int*)d_in[1];
    const int*   dst      = (const int*)d_in[2];
    const float* W1       = (const float*)d_in[3];
    const float* b1       = (const float*)d_in[4];
    const float* W2       = (const float*)d_in[5];
    const float* b2       = (const float*)d_in[6];
    float* out = (float*)d_out;

    const int N = in_sizes[0] / D;   // 50000
    const int E = in_sizes[1];       // 800000
    const int NB = (N + 255) >> 8;   // 196 coarse buckets (<=256 required)

    // ws carve-up
    ushort_t* m1bf   = (ushort_t*)d_ws;                 // N*D
    ushort_t* agg1bf = m1bf + (size_t)N * D;            // N*D
    ushort_t* m2bf   = agg1bf + (size_t)N * D;          // N*D
    ushort_t* W1p    = m2bf + (size_t)N * D;            // 16384
    ushort_t* W2p    = W1p + 16384;                     // 32768
    int*  mat  = (int*)(W2p + 32768);                   // NB*CBLK (histograms)
    int*  matc = mat + (size_t)NB * CBLK;               // NB*CBLK (cursors)
    int*  bb   = matc + (size_t)NB * CBLK;              // NB+1
    int*  offs = bb + NB + 1;                           // N+1
    int2* tmp  = (int2*)(offs + N + 1);                 // E pairs
    int*  bsrc = (int*)(tmp + (size_t)E);               // E

    const int gemmBlocks = (N + 63) / 64;               // 782 (64-row tiles)
    const int gbA = (gemmBlocks * 3) / 5;               // gemm1 share in K3

    const int nPairs = (N + 1) / 2;                     // 25000 waves
    const int gBlocks = (nPairs * 64 + 255) / 256;      // 6250 blocks

    // K1: weight pack || coarse histogram
    packw_binA<<<CBLK + 24, 256, 0, stream>>>(W1, W2, W1p, W2p, dst, mat, E, NB);
    // K2: merged scans -> bucket bases (bb) + per-block cursors (matc)
    binB<<<NB, 256, 0, stream>>>(mat, matc, bb, offs, E, N, NB);
    // K3: coarse binning || gemm1 tiles [0, gbA)
    binC_gemm1<<<CBLK + gbA, 256, 0, stream>>>(src, dst, matc, tmp, E, NB,
                                               features, W1p, b1, m1bf, N);
    // K4: fine sort || gemm1 tiles [gbA, gemmBlocks)
    binD_gemm1<<<NB + (gemmBlocks - gbA), 256, 0, stream>>>(
        tmp, bb, offs, bsrc, N, NB, features, W1p, b1, m1bf, gbA);
    // K5: layer-1 gather -> agg1bf (bf16)
    gather_bf<<<gBlocks, 256, 0, stream>>>(m1bf, offs, bsrc,
                                           agg1bf, nullptr, N);
    // K6: layer-2 GEMM -> out[:,128:] fp32 + m2bf
    gemm2_mfma<<<gemmBlocks, 256, 0, stream>>>(agg1bf, m1bf, W2p, b2,
                                               out + D, m2bf, N);
    // K7: layer-2 gather -> out[:, :128]
    gather_bf<<<gBlocks, 256, 0, stream>>>(m2bf, offs, bsrc,
                                           nullptr, out, N);
}

// Round 10
// 209.784 us; speedup vs baseline: 1.0512x; 1.0081x over previous
//
#include <hip/hip_runtime.h>

// ---------------------------------------------------------------------------
// GNN 2-layer via bf16 MFMA + CSR gather (no global atomics).
// FINAL (= Round-6, best measured 205.5us). Session ledger:
//  - launch merges (pack||binA, binB1+B2, binC||gemm1, binD||gemm1): -5us
//  - 64-row GEMM tiles (782 blocks, 3/CU): -3us
//  - REJECTED by measurement: gather-into-gemm fusion (+55us, kills gather
//    TLP), feature-chunked gather (+78us, strided slice wastes cache lines),
//    atomic CSR build (+50us, 4B scatter write-allocate), 4-sub binD (+10us,
//    4x redundant histograms), gather1/gemm2 half-overlap (+15us, occupancy),
//    2-node-per-wave gather (+6us, VGPR + imbalance).
// Remaining time: 2 gathers at random-access roofline (~40us each, 205MB
// demand vs 12.8MB table > 4MiB/XCD L2), GEMMs+build largely hidden.
// Launches:
//   K1: pack_w || binA        K2: binB
//   K3: binC || gemm1[0..gbA) K4: binD || gemm1[gbA..)
//   K5: gather1 -> agg1bf     K6: gemm2 -> out[:,128:] + m2bf
//   K7: gather2 -> out[:, :128]
// ws: m1bf | agg1bf | m2bf | W1p | W2p | mat | matc | bb | offs | tmp | bsrc
// ---------------------------------------------------------------------------

#define D 128
#define CBLK 256         // coarse-binning blocks (phases A and C)
#define DCAP 6144        // max edges per coarse bucket for LDS path

typedef __attribute__((ext_vector_type(8))) short short8;
typedef __attribute__((ext_vector_type(4))) float float4v;
typedef unsigned short ushort_t;
typedef unsigned int uint_t;

static __device__ __forceinline__ ushort_t f2bf(float f) {
    uint_t u = __builtin_bit_cast(uint_t, f);
    u += 0x7FFFu + ((u >> 16) & 1u);           // RNE
    return (ushort_t)(u >> 16);
}
static __device__ __forceinline__ float bfhi(uint_t u) {
    return __builtin_bit_cast(float, u & 0xFFFF0000u);
}
static __device__ __forceinline__ float bflo(uint_t u) {
    return __builtin_bit_cast(float, u << 16);
}

// ---------------- shared gemm1 body: 64-row tile, wave = 16 rows ------------
static __device__ __forceinline__ void gemm1_body(
    const float* __restrict__ X, const ushort_t* __restrict__ Wp,
    const float* __restrict__ bias, ushort_t* __restrict__ Ybf,
    int N, int gb)
{
    const int wave = threadIdx.x >> 6;
    const int lane = threadIdx.x & 63;
    const int quad = lane >> 4;
    const int l16  = lane & 15;
    const int r0   = gb * 64 + wave * 16;

    float4v acc[8];
    #pragma unroll
    for (int cg = 0; cg < 8; ++cg) {
        float bv = bias[cg * 16 + l16];
        float4v b4 = {bv, bv, bv, bv};
        acc[cg] = b4;
    }

    const short8* wp8 = (const short8*)Wp;

    #pragma unroll
    for (int kb = 0; kb < 4; ++kb) {
        const int k0 = kb * 32 + quad * 8;
        int row = r0 + l16;
        if (row >= N) row = N - 1;
        const float* p = &X[(size_t)row * D + k0];
        float4 x0 = *(const float4*)p;
        float4 x1 = *(const float4*)(p + 4);
        short8 a;
        a[0] = (short)f2bf(x0.x); a[1] = (short)f2bf(x0.y);
        a[2] = (short)f2bf(x0.z); a[3] = (short)f2bf(x0.w);
        a[4] = (short)f2bf(x1.x); a[5] = (short)f2bf(x1.y);
        a[6] = (short)f2bf(x1.z); a[7] = (short)f2bf(x1.w);
        #pragma unroll
        for (int cg = 0; cg < 8; ++cg) {
            short8 b = wp8[(kb * 8 + cg) * 64 + lane];
            acc[cg] = __builtin_amdgcn_mfma_f32_16x16x32_bf16(a, b, acc[cg], 0, 0, 0);
        }
    }

    const int rowb = r0 + quad * 4;
    #pragma unroll
    for (int cg = 0; cg < 8; ++cg) {
        int col = cg * 16 + l16;
        #pragma unroll
        for (int i = 0; i < 4; ++i) {
            int row = rowb + i;
            if (row < N) Ybf[(size_t)row * D + col] = f2bf(acc[cg][i]);
        }
    }
}

// ---------------- K1: pack both W (B-frag layout)  ||  binA -----------------
__global__ __launch_bounds__(256) void packw_binA(
    const float* __restrict__ W1, const float* __restrict__ W2,
    ushort_t* __restrict__ W1p, ushort_t* __restrict__ W2p,
    const int* __restrict__ dst, int* __restrict__ mat, int E, int NB)
{
    __shared__ int h[256];
    if (blockIdx.x < CBLK) {
        const int c = blockIdx.x;
        for (int i = threadIdx.x; i < NB; i += 256) h[i] = 0;
        __syncthreads();
        const int chunk = (E + CBLK - 1) / CBLK;
        int e0 = c * chunk, e1 = e0 + chunk; if (e1 > E) e1 = E;
        for (int e = e0 + threadIdx.x; e < e1; e += 256)
            atomicAdd(&h[dst[e] >> 8], 1);
        __syncthreads();
        for (int i = threadIdx.x; i < NB; i += 256)
            mat[i * CBLK + c] = h[i];
        return;
    }
    const int n1 = 4 * 8 * 64;
    const int n2 = 8 * 8 * 64;
    int t = (blockIdx.x - CBLK) * 256 + threadIdx.x;
    if (t >= n1 + n2) return;
    const float* W; ushort_t* Wp; int tt;
    if (t < n1) { W = W1; Wp = W1p; tt = t; }
    else        { W = W2; Wp = W2p; tt = t - n1; }
    int lane = tt & 63, cg = (tt >> 6) & 7, kb = tt >> 9;
    int krow = kb * 32 + (lane >> 4) * 8;
    int col  = cg * 16 + (lane & 15);
    #pragma unroll
    for (int j = 0; j < 8; ++j)
        Wp[(size_t)tt * 8 + j] = f2bf(W[(size_t)(krow + j) * D + col]);
}

// ---------------- K2: binB (merged B1+B2) -----------------------------------
__global__ __launch_bounds__(256) void binB(
    const int* __restrict__ mat, int* __restrict__ matc,
    int* __restrict__ bb, int* __restrict__ offs, int E, int N, int NB)
{
    __shared__ int s[256];
    __shared__ int ex[256];
    const int b = blockIdx.x;
    const int tid = threadIdx.x;

    int v = 0;
    if (tid < NB) {
        const int* row = &mat[tid * CBLK];
        for (int c = 0; c < CBLK; ++c) v += row[c];
    }
    s[tid] = v; __syncthreads();
    for (int o = 1; o < 256; o <<= 1) {
        int t = (tid >= o) ? s[tid - o] : 0;
        __syncthreads();
        s[tid] += t;
        __syncthreads();
    }
    ex[tid] = s[tid] - v;
    __syncthreads();
    if (b == 0) {
        if (tid < NB) bb[tid] = ex[tid];
        if (tid == 0) { bb[NB] = E; offs[N] = E; }
    }
    const int bbb = ex[b];

    int v2 = mat[b * CBLK + tid];
    __syncthreads();
    s[tid] = v2; __syncthreads();
    for (int o = 1; o < 256; o <<= 1) {
        int t = (tid >= o) ? s[tid - o] : 0;
        __syncthreads();
        s[tid] += t;
        __syncthreads();
    }
    matc[b * CBLK + tid] = bbb + s[tid] - v2;
}

// ---------------- K3: binC  ||  gemm1 part A --------------------------------
__global__ __launch_bounds__(256) void binC_gemm1(
    const int* __restrict__ src, const int* __restrict__ dst,
    const int* __restrict__ matc, int2* __restrict__ tmp, int E, int NB,
    const float* __restrict__ X, const ushort_t* __restrict__ Wp,
    const float* __restrict__ bias, ushort_t* __restrict__ Ybf, int N)
{
    __shared__ int base[256];
    __shared__ int lcnt[256];
    if (blockIdx.x < CBLK) {
        const int c = blockIdx.x;
        for (int i = threadIdx.x; i < NB; i += 256) {
            base[i] = matc[i * CBLK + c];
            lcnt[i] = 0;
        }
        __syncthreads();
        const int chunk = (E + CBLK - 1) / CBLK;
        int e0 = c * chunk, e1 = e0 + chunk; if (e1 > E) e1 = E;
        for (int e = e0 + threadIdx.x; e < e1; e += 256) {
            int d = dst[e];
            int b = d >> 8;
            int p = base[b] + atomicAdd(&lcnt[b], 1);
            int2 pr; pr.x = d; pr.y = src[e];
            tmp[p] = pr;
        }
        return;
    }
    gemm1_body(X, Wp, bias, Ybf, N, blockIdx.x - CBLK);
}

// ---------------- K4: binD (fine sort) || gemm1 part B ----------------------
__global__ __launch_bounds__(256) void binD_gemm1(
    const int2* __restrict__ tmp, const int* __restrict__ bb,
    int* __restrict__ offs, int* __restrict__ bsrc, int N, int NB,
    const float* __restrict__ X, const ushort_t* __restrict__ Wp,
    const float* __restrict__ bias, ushort_t* __restrict__ Ybf, int gb0)
{
    __shared__ int hist[256];
    __shared__ int foff[256];
    __shared__ int cntf[256];
    __shared__ int outS[DCAP];
    if (blockIdx.x >= (uint_t)NB) {
        gemm1_body(X, Wp, bias, Ybf, N, blockIdx.x - NB + gb0);
        return;
    }
    const int b = blockIdx.x;
    const int tid = threadIdx.x;
    const int beg = bb[b], end = bb[b + 1];
    const int cnt = end - beg;
    const int n0 = b << 8;

    hist[tid] = 0;
    __syncthreads();
    for (int i = tid; i < cnt; i += 256)
        atomicAdd(&hist[tmp[beg + i].x & 255], 1);
    __syncthreads();
    int v = hist[tid];
    __syncthreads();
    hist[tid] = v; __syncthreads();
    for (int o = 1; o < 256; o <<= 1) {
        int t = (tid >= o) ? hist[tid - o] : 0;
        __syncthreads();
        hist[tid] += t;
        __syncthreads();
    }
    foff[tid] = hist[tid] - v;
    cntf[tid] = 0;
    __syncthreads();

    int node = n0 + tid;
    if (node < N) offs[node] = beg + foff[tid];

    if (cnt <= DCAP) {
        for (int i = tid; i < cnt; i += 256) {
            int2 p = tmp[beg + i];
            int f = p.x & 255;
            int pos = foff[f] + atomicAdd(&cntf[f], 1);
            outS[pos] = p.y;
        }
        __syncthreads();
        for (int i = tid; i < cnt; i += 256)
            bsrc[beg + i] = outS[i];
    } else {
        for (int i = tid; i < cnt; i += 256) {
            int2 p = tmp[beg + i];
            int f = p.x & 255;
            int pos = foff[f] + atomicAdd(&cntf[f], 1);
            bsrc[beg + pos] = p.y;
        }
    }
}

// ---------------- K6: MFMA GEMM 2 (64-row tile): bf16 A0/A1 -> fp32 + bf16 --
__global__ __launch_bounds__(256) void gemm2_mfma(
    const ushort_t* __restrict__ A0, const ushort_t* __restrict__ A1,
    const ushort_t* __restrict__ Wp, const float* __restrict__ bias,
    float* __restrict__ Yf, ushort_t* __restrict__ Ybf, int N)
{
    const int wave = threadIdx.x >> 6;
    const int lane = threadIdx.x & 63;
    const int quad = lane >> 4;
    const int l16  = lane & 15;
    const int r0   = blockIdx.x * 64 + wave * 16;

    float4v acc[8];
    #pragma unroll
    for (int cg = 0; cg < 8; ++cg) {
        float bv = bias[cg * 16 + l16];
        float4v b4 = {bv, bv, bv, bv};
        acc[cg] = b4;
    }

    const short8* wp8 = (const short8*)Wp;

    #pragma unroll
    for (int kb = 0; kb < 8; ++kb) {
        const ushort_t* __restrict__ A = (kb < 4) ? A0 : A1;
        const int k0 = (kb & 3) * 32 + quad * 8;
        int row = r0 + l16;
        if (row >= N) row = N - 1;
        short8 a = *(const short8*)&A[(size_t)row * D + k0];
        #pragma unroll
        for (int cg = 0; cg < 8; ++cg) {
            short8 b = wp8[(kb * 8 + cg) * 64 + lane];
            acc[cg] = __builtin_amdgcn_mfma_f32_16x16x32_bf16(a, b, acc[cg], 0, 0, 0);
        }
    }

    const int rowb = r0 + quad * 4;
    #pragma unroll
    for (int cg = 0; cg < 8; ++cg) {
        int col = cg * 16 + l16;
        #pragma unroll
        for (int i = 0; i < 4; ++i) {
            int row = rowb + i;
            if (row < N) {
                float v = acc[cg][i];
                Yf[(size_t)row * 256 + col] = v;
                Ybf[(size_t)row * D + col] = f2bf(v);
            }
        }
    }
}

// ---------------- K5/K7: gather-sum over CSR (bf16 msg), quad-split ---------
__global__ __launch_bounds__(256) void gather_bf(
    const ushort_t* __restrict__ msg,            // [N][128] bf16
    const int* __restrict__ offs, const int* __restrict__ bsrc,
    ushort_t* __restrict__ aggB,                 // bf16 out [N][128], or null
    float* __restrict__ aggF,                    // fp32 out (stride 256), or null
    int N)
{
    int node = (blockIdx.x * 256 + threadIdx.x) >> 6;
    int lane = threadIdx.x & 63;
    if (node >= N) return;
    const int quad = lane >> 4;
    const int c16  = lane & 15;
    int beg = offs[node], end = offs[node + 1];

    float ax[4] = {0.f, 0.f, 0.f, 0.f};
    float ay[4] = {0.f, 0.f, 0.f, 0.f};
    const uint4* mp = (const uint4*)msg;         // 16 uint4 per row

    for (int base = beg; base < end; base += 64) {
        int cnt = end - base; if (cnt > 64) cnt = 64;
        int sidx = bsrc[base + (lane < cnt ? lane : cnt - 1)];
        for (int j0 = 0; j0 < cnt; j0 += 16) {
            #pragma unroll
            for (int t = 0; t < 4; ++t) {
                int e  = j0 + t * 4 + quad;
                int ec = (e < cnt) ? e : cnt - 1;
                int s  = __shfl(sidx, ec, 64);
                uint4 u = mp[(size_t)s * 16 + c16];
                if (e < cnt) {
                    ax[0] += bflo(u.x); ay[0] += bfhi(u.x);
                    ax[1] += bflo(u.y); ay[1] += bfhi(u.y);
                    ax[2] += bflo(u.z); ay[2] += bfhi(u.z);
                    ax[3] += bflo(u.w); ay[3] += bfhi(u.w);
                }
            }
        }
    }

    #pragma unroll
    for (int k = 0; k < 4; ++k) {
        ax[k] += __shfl_xor(ax[k], 16, 64);
        ax[k] += __shfl_xor(ax[k], 32, 64);
        ay[k] += __shfl_xor(ay[k], 16, 64);
        ay[k] += __shfl_xor(ay[k], 32, 64);
    }

    if (quad == 0) {
        if (aggB) {
            uint4 o;
            o.x = (uint_t)f2bf(ax[0]) | ((uint_t)f2bf(ay[0]) << 16);
            o.y = (uint_t)f2bf(ax[1]) | ((uint_t)f2bf(ay[1]) << 16);
            o.z = (uint_t)f2bf(ax[2]) | ((uint_t)f2bf(ay[2]) << 16);
            o.w = (uint_t)f2bf(ax[3]) | ((uint_t)f2bf(ay[3]) << 16);
            ((uint4*)aggB)[(size_t)node * 16 + c16] = o;
        } else {
            float4 w0 = {ax[0], ay[0], ax[1], ay[1]};
            float4 w1 = {ax[2], ay[2], ax[3], ay[3]};
            float* p = &aggF[(size_t)node * 256 + c16 * 8];
            *(float4*)p = w0;
            *(float4*)(p + 4) = w1;
        }
    }
}

// ---------------------------------------------------------------------------
extern "C" void kernel_launch(void* const* d_in, const int* in_sizes, int n_in,
                              void* d_out, int out_size, void* d_ws, size_t ws_size,
                              hipStream_t stream) {
    const float* features = (const float*)d_in[0];
    const int*   src      = (const int*)d_in[1];
    const int*   dst      = (const int*)d_in[2];
    const float* W1       = (const float*)d_in[3];
    const float* b1       = (const float*)d_in[4];
    const float* W2       = (const float*)d_in[5];
    const float* b2       = (const float*)d_in[6];
    float* out = (float*)d_out;

    const int N = in_sizes[0] / D;   // 50000
    const int E = in_sizes[1];       // 800000
    const int NB = (N + 255) >> 8;   // 196 coarse buckets (<=256 required)

    // ws carve-up
    ushort_t* m1bf   = (ushort_t*)d_ws;                 // N*D
    ushort_t* agg1bf = m1bf + (size_t)N * D;            // N*D
    ushort_t* m2bf   = agg1bf + (size_t)N * D;          // N*D
    ushort_t* W1p    = m2bf + (size_t)N * D;            // 16384
    ushort_t* W2p    = W1p + 16384;                     // 32768
    int*  mat  = (int*)(W2p + 32768);                   // NB*CBLK (histograms)
    int*  matc = mat + (size_t)NB * CBLK;               // NB*CBLK (cursors)
    int*  bb   = matc + (size_t)NB * CBLK;              // NB+1
    int*  offs = bb + NB + 1;                           // N+1
    int2* tmp  = (int2*)(offs + N + 1);                 // E pairs
    int*  bsrc = (int*)(tmp + (size_t)E);               // E

    const int gemmBlocks = (N + 63) / 64;               // 782 (64-row tiles)
    const int gbA = gemmBlocks / 2;                     // gemm1 share in K3

    // K1: weight pack || coarse histogram
    packw_binA<<<CBLK + 24, 256, 0, stream>>>(W1, W2, W1p, W2p, dst, mat, E, NB);
    // K2: merged scans -> bucket bases (bb) + per-block cursors (matc)
    binB<<<NB, 256, 0, stream>>>(mat, matc, bb, offs, E, N, NB);
    // K3: coarse binning || gemm1 tiles [0, gbA)
    binC_gemm1<<<CBLK + gbA, 256, 0, stream>>>(src, dst, matc, tmp, E, NB,
                                               features, W1p, b1, m1bf, N);
    // K4: fine sort || gemm1 tiles [gbA, gemmBlocks)
    binD_gemm1<<<NB + (gemmBlocks - gbA), 256, 0, stream>>>(
        tmp, bb, offs, bsrc, N, NB, features, W1p, b1, m1bf, gbA);
    // K5: layer-1 gather -> agg1bf (bf16)
    gather_bf<<<(N * 64 + 255) / 256, 256, 0, stream>>>(m1bf, offs, bsrc,
                                                        agg1bf, nullptr, N);
    // K6: layer-2 GEMM -> out[:,128:] fp32 + m2bf
    gemm2_mfma<<<gemmBlocks, 256, 0, stream>>>(agg1bf, m1bf, W2p, b2,
                                               out + D, m2bf, N);
    // K7: layer-2 gather -> out[:, :128]
    gather_bf<<<(N * 64 + 255) / 256, 256, 0, stream>>>(m2bf, offs, bsrc,
                                                        nullptr, out, N);
}